// Round 1
// baseline (388.639 us; speedup 1.0000x reference)
//
#include <hip/hip_runtime.h>
#include <cstdint>
#include <cstddef>

typedef __bf16 bf16;
typedef __bf16 bf16x8 __attribute__((ext_vector_type(8)));
typedef __bf16 bf16x4 __attribute__((ext_vector_type(4)));
typedef float  f32x4  __attribute__((ext_vector_type(4)));

#define MFMA16(a, b, c) __builtin_amdgcn_mfma_f32_16x16x32_bf16((a), (b), (c), 0, 0, 0)

static constexpr int BB   = 4;
static constexpr int TT   = 2048;
static constexpr int DM   = 1024;
static constexpr int NH   = 16;
static constexpr int HD   = 64;
static constexpr int TOK  = BB * TT;    // 8192
static constexpr int NQKV = 3 * DM;     // 3072

// ---------------- elementwise f32 -> bf16 ----------------
__global__ void k_cvt(const float* __restrict__ in, bf16* __restrict__ out, int n) {
    int i = (blockIdx.x * blockDim.x + threadIdx.x) * 4;
    if (i >= n) return;
    float4 v = *(const float4*)(in + i);
    bf16x4 o;
    o[0] = (bf16)v.x; o[1] = (bf16)v.y; o[2] = (bf16)v.z; o[3] = (bf16)v.w;
    *(bf16x4*)(out + i) = o;
}

// ---------------- transpose + convert: in f32 [R][C] -> out bf16 [C][R] ----------------
__global__ void k_transpose_cvt(const float* __restrict__ in, bf16* __restrict__ out,
                                int R, int C) {
    __shared__ bf16 tl[64 * 72];
    int tid = threadIdx.x;
    int c0 = blockIdx.x * 64, r0 = blockIdx.y * 64;
#pragma unroll
    for (int rep = 0; rep < 4; rep++) {
        int r = rep * 16 + (tid >> 4);
        int c = (tid & 15) * 4;
        float4 v = *(const float4*)(in + (size_t)(r0 + r) * C + c0 + c);
        tl[r * 72 + c + 0] = (bf16)v.x;
        tl[r * 72 + c + 1] = (bf16)v.y;
        tl[r * 72 + c + 2] = (bf16)v.z;
        tl[r * 72 + c + 3] = (bf16)v.w;
    }
    __syncthreads();
#pragma unroll
    for (int rep = 0; rep < 4; rep++) {
        int cc = rep * 16 + (tid >> 4);
        int rr = (tid & 15) * 4;
        bf16x4 o;
        o[0] = tl[(rr + 0) * 72 + cc];
        o[1] = tl[(rr + 1) * 72 + cc];
        o[2] = tl[(rr + 2) * 72 + cc];
        o[3] = tl[(rr + 3) * 72 + cc];
        *(bf16x4*)(out + (size_t)(c0 + cc) * R + r0 + rr) = o;
    }
}

// ---------------- RoPE cos/sin table ----------------
__global__ void k_rope_tab(float* __restrict__ ct, float* __restrict__ st) {
    int i = blockIdx.x * blockDim.x + threadIdx.x;   // TT*32
    int t = i >> 5, j = i & 31;
    float invf = powf(10000.0f, -(float)j * (1.0f / 32.0f));
    float a = (float)t * invf;
    ct[i] = cosf(a);
    st[i] = sinf(a);
}

// ---------------- RoPE in-place on [B*H, T, 64] bf16 (scale folds 1/sqrt(hd) for Q) ----------------
__global__ void k_rope_ip(bf16* __restrict__ buf, const float* __restrict__ ct,
                          const float* __restrict__ st, float scale) {
    int i = blockIdx.x * blockDim.x + threadIdx.x;   // < B*H*T
    int t = i & (TT - 1);
    bf16* p = buf + (size_t)i * HD;
    float x[64];
#pragma unroll
    for (int w = 0; w < 8; w++) {
        bf16x8 v = *(const bf16x8*)(p + w * 8);
#pragma unroll
        for (int e = 0; e < 8; e++) x[w * 8 + e] = (float)v[e];
    }
    const float* crow = ct + t * 32;
    const float* srow = st + t * 32;
#pragma unroll
    for (int d = 0; d < 32; d++) {
        float cs = crow[d], sn = srow[d];
        float a = x[d], b2 = x[d + 32];
        x[d]      = scale * (a  * cs - b2 * sn);
        x[d + 32] = scale * (b2 * cs + a  * sn);
    }
#pragma unroll
    for (int w = 0; w < 8; w++) {
        bf16x8 v;
#pragma unroll
        for (int e = 0; e < 8; e++) v[e] = (bf16)x[w * 8 + e];
        *(bf16x8*)(p + w * 8) = v;
    }
}

// ---------------- GEMM: C[M][N] = A[M][K] @ Bt[N][K]^T, bf16 in, f32 acc ----------------
// MODE 1: scatter epilogue -> qbuf/kbuf [B,H,T,64], vbuf [B,H,64,T] (QKV projection)
// MODE 2: f32 row-major out (final projection)
template <int MODE>
__global__ __launch_bounds__(256) void k_gemm_bt(
    const bf16* __restrict__ A, const bf16* __restrict__ Bt,
    int M, int N, int K,
    float* __restrict__ outF,
    bf16* __restrict__ qbuf, bf16* __restrict__ kbuf, bf16* __restrict__ vbuf) {
    __shared__ bf16 lA[128 * 72];
    __shared__ bf16 lB[128 * 72];
    int tid = threadIdx.x;
    int l = tid & 63, wid = tid >> 6;
    int wm = wid >> 1, wn = wid & 1;                 // 2x2 waves of 64x64
    int bn = blockIdx.x, bm = blockIdx.y;
    const bf16* Ab = A + (size_t)bm * 128 * K;
    const bf16* Bb = Bt + (size_t)bn * 128 * K;
    int sr = tid >> 3, scg = (tid & 7) * 8;
    f32x4 acc[4][4] = {};
    for (int kt = 0; kt < K; kt += 64) {
        bf16x8 va[4], vbr[4];
#pragma unroll
        for (int it = 0; it < 4; it++) {
            va[it]  = *(const bf16x8*)(Ab + (size_t)(it * 32 + sr) * K + kt + scg);
            vbr[it] = *(const bf16x8*)(Bb + (size_t)(it * 32 + sr) * K + kt + scg);
        }
        __syncthreads();
#pragma unroll
        for (int it = 0; it < 4; it++) {
            *(bf16x8*)&lA[(it * 32 + sr) * 72 + scg] = va[it];
            *(bf16x8*)&lB[(it * 32 + sr) * 72 + scg] = vbr[it];
        }
        __syncthreads();
#pragma unroll
        for (int kk = 0; kk < 2; kk++) {
            bf16x8 af[4], bfr[4];
#pragma unroll
            for (int mi = 0; mi < 4; mi++)
                af[mi] = *(const bf16x8*)&lA[(wm * 64 + mi * 16 + (l & 15)) * 72 + kk * 32 + (l >> 4) * 8];
#pragma unroll
            for (int ni = 0; ni < 4; ni++)
                bfr[ni] = *(const bf16x8*)&lB[(wn * 64 + ni * 16 + (l & 15)) * 72 + kk * 32 + (l >> 4) * 8];
#pragma unroll
            for (int mi = 0; mi < 4; mi++)
#pragma unroll
                for (int ni = 0; ni < 4; ni++)
                    acc[mi][ni] = MFMA16(af[mi], bfr[ni], acc[mi][ni]);
        }
    }
    if (MODE == 2) {
#pragma unroll
        for (int mi = 0; mi < 4; mi++) {
            int m0 = bm * 128 + wm * 64 + mi * 16 + ((l >> 4) << 2);
#pragma unroll
            for (int ni = 0; ni < 4; ni++) {
                int n = bn * 128 + wn * 64 + ni * 16 + (l & 15);
#pragma unroll
                for (int rj = 0; rj < 4; rj++)
                    outF[(size_t)(m0 + rj) * N + n] = acc[mi][ni][rj];
            }
        }
    } else {
#pragma unroll
        for (int ni = 0; ni < 4; ni++) {
            int n = bn * 128 + wn * 64 + ni * 16 + (l & 15);
            int s = n >> 10, rem = n & 1023;
            int h = rem >> 6, d = rem & 63;
#pragma unroll
            for (int mi = 0; mi < 4; mi++) {
                int m0 = bm * 128 + wm * 64 + mi * 16 + ((l >> 4) << 2);
                int b = m0 >> 11, t0 = m0 & 2047;
                if (s == 2) {
                    bf16x4 pv;
#pragma unroll
                    for (int rj = 0; rj < 4; rj++) pv[rj] = (bf16)acc[mi][ni][rj];
                    *(bf16x4*)(vbuf + ((size_t)((b * NH + h) * HD + d)) * TT + t0) = pv;
                } else {
                    bf16* dst = (s == 0 ? qbuf : kbuf) + ((size_t)(b * NH + h) * TT + t0) * HD + d;
#pragma unroll
                    for (int rj = 0; rj < 4; rj++) dst[(size_t)rj * HD] = (bf16)acc[mi][ni][rj];
                }
            }
        }
    }
}

// ---------------- flash attention: Q,K [B*H,T,64] (Q pre-scaled+roped), Vt [B*H,64,T] ----------------
__global__ __launch_bounds__(256) void k_attn(
    const bf16* __restrict__ Q, const bf16* __restrict__ K,
    const bf16* __restrict__ Vt, bf16* __restrict__ O) {
    __shared__ bf16 lP[128 * 72];   // per-wave-private 32-row stripes
    int tid = threadIdx.x;
    int l = tid & 63, wid = tid >> 6;
    int qt = blockIdx.x, bh = blockIdx.y;
    const bf16* Qb = Q + ((size_t)bh * TT + qt * 128) * HD;
    const bf16* Kb = K + (size_t)bh * TT * HD;
    const bf16* Vb = Vt + (size_t)bh * HD * TT;

    bf16x8 qa[2][2];
#pragma unroll
    for (int mi = 0; mi < 2; mi++)
#pragma unroll
        for (int kk = 0; kk < 2; kk++)
            qa[mi][kk] = *(const bf16x8*)(Qb + (size_t)(wid * 32 + mi * 16 + (l & 15)) * HD + kk * 32 + (l >> 4) * 8);

    f32x4 oacc[2][4] = {};
    float mrun[2][4], lrun[2][4];
#pragma unroll
    for (int mi = 0; mi < 2; mi++)
#pragma unroll
        for (int rj = 0; rj < 4; rj++) { mrun[mi][rj] = -1e30f; lrun[mi][rj] = 0.0f; }

    int nblk = 2 * qt + 2;
    int wrow = qt * 128 + wid * 32;                  // wave's first global row
    for (int j = 0; j < nblk; j++) {
        if (j * 64 > wrow + 31) continue;            // fully-masked for this wave; no barriers in loop
        const bf16* Kj = Kb + (size_t)j * 64 * HD;
        f32x4 sc[2][4] = {};
#pragma unroll
        for (int kk = 0; kk < 2; kk++) {
            bf16x8 kb[4];
#pragma unroll
            for (int nj = 0; nj < 4; nj++)
                kb[nj] = *(const bf16x8*)(Kj + (size_t)(nj * 16 + (l & 15)) * HD + kk * 32 + (l >> 4) * 8);
#pragma unroll
            for (int mi = 0; mi < 2; mi++)
#pragma unroll
                for (int nj = 0; nj < 4; nj++)
                    sc[mi][nj] = MFMA16(qa[mi][kk], kb[nj], sc[mi][nj]);
        }
        if (j >= 2 * qt) {                           // diagonal blocks: causal mask
#pragma unroll
            for (int mi = 0; mi < 2; mi++) {
                int row0 = wrow + mi * 16 + ((l >> 4) << 2);
#pragma unroll
                for (int nj = 0; nj < 4; nj++) {
                    int col = j * 64 + nj * 16 + (l & 15);
#pragma unroll
                    for (int rj = 0; rj < 4; rj++)
                        if (col > row0 + rj) sc[mi][nj][rj] = -1e30f;
                }
            }
        }
        // online softmax
#pragma unroll
        for (int mi = 0; mi < 2; mi++) {
            float rmax[4];
#pragma unroll
            for (int rj = 0; rj < 4; rj++) {
                float v0 = fmaxf(fmaxf(sc[mi][0][rj], sc[mi][1][rj]),
                                 fmaxf(sc[mi][2][rj], sc[mi][3][rj]));
#pragma unroll
                for (int off = 1; off < 16; off <<= 1) v0 = fmaxf(v0, __shfl_xor(v0, off, 64));
                rmax[rj] = v0;
            }
#pragma unroll
            for (int rj = 0; rj < 4; rj++) {
                float nm = fmaxf(mrun[mi][rj], rmax[rj]);
                float alpha = __expf(mrun[mi][rj] - nm);
                mrun[mi][rj] = nm;
                float ssum = 0.0f;
#pragma unroll
                for (int nj = 0; nj < 4; nj++) {
                    float p = __expf(sc[mi][nj][rj] - nm);
                    sc[mi][nj][rj] = p;
                    ssum += p;
                }
#pragma unroll
                for (int off = 1; off < 16; off <<= 1) ssum += __shfl_xor(ssum, off, 64);
                lrun[mi][rj] = lrun[mi][rj] * alpha + ssum;
#pragma unroll
                for (int nd = 0; nd < 4; nd++) oacc[mi][nd][rj] *= alpha;
            }
        }
        // P -> LDS (bf16), per-wave-private rows
#pragma unroll
        for (int mi = 0; mi < 2; mi++) {
            int pr0 = wid * 32 + mi * 16 + ((l >> 4) << 2);
#pragma unroll
            for (int nj = 0; nj < 4; nj++) {
                int pc = nj * 16 + (l & 15);
#pragma unroll
                for (int rj = 0; rj < 4; rj++)
                    lP[(pr0 + rj) * 72 + pc] = (bf16)sc[mi][nj][rj];
            }
        }
        // PV
#pragma unroll
        for (int kk = 0; kk < 2; kk++) {
            bf16x8 pa[2];
#pragma unroll
            for (int mi = 0; mi < 2; mi++)
                pa[mi] = *(const bf16x8*)&lP[(wid * 32 + mi * 16 + (l & 15)) * 72 + kk * 32 + (l >> 4) * 8];
            bf16x8 vb[4];
#pragma unroll
            for (int nd = 0; nd < 4; nd++)
                vb[nd] = *(const bf16x8*)(Vb + (size_t)(nd * 16 + (l & 15)) * TT + j * 64 + kk * 32 + (l >> 4) * 8);
#pragma unroll
            for (int mi = 0; mi < 2; mi++)
#pragma unroll
                for (int nd = 0; nd < 4; nd++)
                    oacc[mi][nd] = MFMA16(pa[mi], vb[nd], oacc[mi][nd]);
        }
    }
    // epilogue: O[tok][h*64+d] bf16
    int b = bh >> 4, h = bh & 15;
#pragma unroll
    for (int mi = 0; mi < 2; mi++) {
#pragma unroll
        for (int rj = 0; rj < 4; rj++) {
            int t = qt * 128 + wid * 32 + mi * 16 + ((l >> 4) << 2) + rj;
            float inv = 1.0f / lrun[mi][rj];
            size_t base = ((size_t)b * TT + t) * DM + h * HD;
#pragma unroll
            for (int nd = 0; nd < 4; nd++)
                O[base + nd * 16 + (l & 15)] = (bf16)(oacc[mi][nd][rj] * inv);
        }
    }
}

extern "C" void kernel_launch(void* const* d_in, const int* in_sizes, int n_in,
                              void* d_out, int out_size, void* d_ws, size_t ws_size,
                              hipStream_t stream) {
    const float* x    = (const float*)d_in[0];
    const float* Wqkv = (const float*)d_in[1];
    const float* Wout = (const float*)d_in[2];
    float* out = (float*)d_out;

    char* ws = (char*)d_ws;
    size_t off = 0;
    auto alloc = [&](size_t bytes) {
        void* p = ws + off;
        off += (bytes + 255) & ~(size_t)255;
        return p;
    };
    bf16* xb    = (bf16*)alloc((size_t)TOK * DM * 2);
    bf16* wqkvt = (bf16*)alloc((size_t)NQKV * DM * 2);
    bf16* woutt = (bf16*)alloc((size_t)DM * DM * 2);
    bf16* qr    = (bf16*)alloc((size_t)TOK * DM * 2);
    bf16* kr    = (bf16*)alloc((size_t)TOK * DM * 2);
    bf16* vt    = (bf16*)alloc((size_t)TOK * DM * 2);
    bf16* ob    = (bf16*)alloc((size_t)TOK * DM * 2);
    float* ct   = (float*)alloc((size_t)TT * 32 * 4);
    float* st   = (float*)alloc((size_t)TT * 32 * 4);
    (void)ws_size; (void)in_sizes; (void)n_in; (void)out_size;

    k_cvt<<<TOK * DM / 4 / 256, 256, 0, stream>>>(x, xb, TOK * DM);
    k_transpose_cvt<<<dim3(NQKV / 64, DM / 64), 256, 0, stream>>>(Wqkv, wqkvt, DM, NQKV);
    k_transpose_cvt<<<dim3(DM / 64, DM / 64), 256, 0, stream>>>(Wout, woutt, DM, DM);
    k_rope_tab<<<TT * 32 / 256, 256, 0, stream>>>(ct, st);
    k_gemm_bt<1><<<dim3(NQKV / 128, TOK / 128), 256, 0, stream>>>(
        xb, wqkvt, TOK, NQKV, DM, nullptr, qr, kr, vt);
    k_rope_ip<<<BB * NH * TT / 256, 256, 0, stream>>>(qr, ct, st, 0.125f);
    k_rope_ip<<<BB * NH * TT / 256, 256, 0, stream>>>(kr, ct, st, 1.0f);
    k_attn<<<dim3(TT / 128, BB * NH), 256, 0, stream>>>(qr, kr, vt, ob);
    k_gemm_bt<2><<<dim3(DM / 128, TOK / 128), 256, 0, stream>>>(
        ob, woutt, TOK, DM, DM, out, nullptr, nullptr, nullptr);
}

// Round 2
// 317.885 us; speedup vs baseline: 1.2226x; 1.2226x over previous
//
#include <hip/hip_runtime.h>
#include <cstdint>
#include <cstddef>

typedef __bf16 bf16;
typedef __bf16 bf16x8 __attribute__((ext_vector_type(8)));
typedef __bf16 bf16x4 __attribute__((ext_vector_type(4)));
typedef float  f32x4  __attribute__((ext_vector_type(4)));

#define MFMA16(a, b, c) __builtin_amdgcn_mfma_f32_16x16x32_bf16((a), (b), (c), 0, 0, 0)

static constexpr int BB   = 4;
static constexpr int TT   = 2048;
static constexpr int DM   = 1024;
static constexpr int NH   = 16;
static constexpr int HD   = 64;
static constexpr int TOK  = BB * TT;    // 8192
static constexpr int NQKV = 3 * DM;     // 3072

// async global->LDS, 16B per lane; dst must be wave-uniform base (HW adds lane*16)
__device__ inline void gload16(const void* g, void* l) {
    __builtin_amdgcn_global_load_lds((const __attribute__((address_space(1))) void*)g,
                                     (__attribute__((address_space(3))) void*)l, 16, 0, 0);
}

// ---------------- elementwise f32 -> bf16 ----------------
__global__ void k_cvt(const float* __restrict__ in, bf16* __restrict__ out, int n) {
    int i = (blockIdx.x * blockDim.x + threadIdx.x) * 4;
    if (i >= n) return;
    float4 v = *(const float4*)(in + i);
    bf16x4 o;
    o[0] = (bf16)v.x; o[1] = (bf16)v.y; o[2] = (bf16)v.z; o[3] = (bf16)v.w;
    *(bf16x4*)(out + i) = o;
}

// ---------------- transpose + convert: in f32 [R][C] -> out bf16 [C][R] ----------------
__global__ void k_transpose_cvt(const float* __restrict__ in, bf16* __restrict__ out,
                                int R, int C) {
    __shared__ bf16 tl[64 * 72];
    int tid = threadIdx.x;
    int c0 = blockIdx.x * 64, r0 = blockIdx.y * 64;
#pragma unroll
    for (int rep = 0; rep < 4; rep++) {
        int r = rep * 16 + (tid >> 4);
        int c = (tid & 15) * 4;
        float4 v = *(const float4*)(in + (size_t)(r0 + r) * C + c0 + c);
        tl[r * 72 + c + 0] = (bf16)v.x;
        tl[r * 72 + c + 1] = (bf16)v.y;
        tl[r * 72 + c + 2] = (bf16)v.z;
        tl[r * 72 + c + 3] = (bf16)v.w;
    }
    __syncthreads();
#pragma unroll
    for (int rep = 0; rep < 4; rep++) {
        int cc = rep * 16 + (tid >> 4);
        int rr = (tid & 15) * 4;
        bf16x4 o;
        o[0] = tl[(rr + 0) * 72 + cc];
        o[1] = tl[(rr + 1) * 72 + cc];
        o[2] = tl[(rr + 2) * 72 + cc];
        o[3] = tl[(rr + 3) * 72 + cc];
        *(bf16x4*)(out + (size_t)(c0 + cc) * R + r0 + rr) = o;
    }
}

// ---------------- RoPE cos/sin table ----------------
__global__ void k_rope_tab(float* __restrict__ ct, float* __restrict__ st) {
    int i = blockIdx.x * blockDim.x + threadIdx.x;   // TT*32
    int t = i >> 5, j = i & 31;
    float invf = powf(10000.0f, -(float)j * (1.0f / 32.0f));
    float a = (float)t * invf;
    ct[i] = cosf(a);
    st[i] = sinf(a);
}

// ---------------- RoPE in-place on [B*H, T, 64] bf16 (scale folds 1/sqrt(hd) for Q) ----------------
__global__ void k_rope_ip(bf16* __restrict__ buf, const float* __restrict__ ct,
                          const float* __restrict__ st, float scale) {
    int i = blockIdx.x * blockDim.x + threadIdx.x;   // < B*H*T
    int t = i & (TT - 1);
    bf16* p = buf + (size_t)i * HD;
    float x[64];
#pragma unroll
    for (int w = 0; w < 8; w++) {
        bf16x8 v = *(const bf16x8*)(p + w * 8);
#pragma unroll
        for (int e = 0; e < 8; e++) x[w * 8 + e] = (float)v[e];
    }
    const float* crow = ct + t * 32;
    const float* srow = st + t * 32;
#pragma unroll
    for (int d = 0; d < 32; d++) {
        float cs = crow[d], sn = srow[d];
        float a = x[d], b2 = x[d + 32];
        x[d]      = scale * (a  * cs - b2 * sn);
        x[d + 32] = scale * (b2 * cs + a  * sn);
    }
#pragma unroll
    for (int w = 0; w < 8; w++) {
        bf16x8 v;
#pragma unroll
        for (int e = 0; e < 8; e++) v[e] = (bf16)x[w * 8 + e];
        *(bf16x8*)(p + w * 8) = v;
    }
}

// ---------------- GEMM: C[M][N] = A[M][K] @ Bt[N][K]^T, bf16 in, f32 acc ----------------
// m97 structure: global_load_lds width=16, linear [128][64] LDS, 2 barriers/K-step.
// MODE 1: scatter epilogue -> qbuf/kbuf [B,H,T,64], vbuf [B,H,64,T] (QKV projection)
// MODE 2: f32 row-major out (final projection)
template <int MODE>
__global__ __launch_bounds__(256) void k_gemm_bt(
    const bf16* __restrict__ A, const bf16* __restrict__ Bt,
    int M, int N, int K,
    float* __restrict__ outF,
    bf16* __restrict__ qbuf, bf16* __restrict__ kbuf, bf16* __restrict__ vbuf) {
    __shared__ bf16 lA[128 * 64];
    __shared__ bf16 lB[128 * 64];
    int tid = threadIdx.x;
    int l = tid & 63, wid = tid >> 6;
    int wm = wid >> 1, wn = wid & 1;                 // 2x2 waves of 64x64
    int bn = blockIdx.x, bm = blockIdx.y;
    const bf16* Ab = A + (size_t)bm * 128 * K;
    const bf16* Bb = Bt + (size_t)bn * 128 * K;
    int srow = l >> 3, scol = (l & 7) * 8;           // within an 8-row chunk
    f32x4 acc[4][4] = {};
    for (int kt = 0; kt < K; kt += 64) {
        __syncthreads();                             // previous iter's ds_reads done
#pragma unroll
        for (int i = 0; i < 4; i++) {
            int chunk = wid * 4 + i;                 // 16 chunks x 512 elems (8 rows)
            gload16(Ab + (size_t)(chunk * 8 + srow) * K + kt + scol, &lA[chunk * 512]);
            gload16(Bb + (size_t)(chunk * 8 + srow) * K + kt + scol, &lB[chunk * 512]);
        }
        __syncthreads();                             // drains vmcnt (compiler-emitted)
#pragma unroll
        for (int kk = 0; kk < 2; kk++) {
            bf16x8 af[4], bfr[4];
#pragma unroll
            for (int mi = 0; mi < 4; mi++)
                af[mi] = *(const bf16x8*)&lA[(wm * 64 + mi * 16 + (l & 15)) * 64 + kk * 32 + (l >> 4) * 8];
#pragma unroll
            for (int ni = 0; ni < 4; ni++)
                bfr[ni] = *(const bf16x8*)&lB[(wn * 64 + ni * 16 + (l & 15)) * 64 + kk * 32 + (l >> 4) * 8];
#pragma unroll
            for (int mi = 0; mi < 4; mi++)
#pragma unroll
                for (int ni = 0; ni < 4; ni++)
                    acc[mi][ni] = MFMA16(af[mi], bfr[ni], acc[mi][ni]);
        }
    }
    if (MODE == 2) {
#pragma unroll
        for (int mi = 0; mi < 4; mi++) {
            int m0 = bm * 128 + wm * 64 + mi * 16 + ((l >> 4) << 2);
#pragma unroll
            for (int ni = 0; ni < 4; ni++) {
                int n = bn * 128 + wn * 64 + ni * 16 + (l & 15);
#pragma unroll
                for (int rj = 0; rj < 4; rj++)
                    outF[(size_t)(m0 + rj) * N + n] = acc[mi][ni][rj];
            }
        }
    } else {
#pragma unroll
        for (int ni = 0; ni < 4; ni++) {
            int n = bn * 128 + wn * 64 + ni * 16 + (l & 15);
            int s = n >> 10, rem = n & 1023;
            int h = rem >> 6, d = rem & 63;
#pragma unroll
            for (int mi = 0; mi < 4; mi++) {
                int m0 = bm * 128 + wm * 64 + mi * 16 + ((l >> 4) << 2);
                int b = m0 >> 11, t0 = m0 & 2047;
                if (s == 2) {
                    bf16x4 pv;
#pragma unroll
                    for (int rj = 0; rj < 4; rj++) pv[rj] = (bf16)acc[mi][ni][rj];
                    *(bf16x4*)(vbuf + ((size_t)((b * NH + h) * HD + d)) * TT + t0) = pv;
                } else {
                    bf16* dst = (s == 0 ? qbuf : kbuf) + ((size_t)(b * NH + h) * TT + t0) * HD + d;
#pragma unroll
                    for (int rj = 0; rj < 4; rj++) dst[(size_t)rj * HD] = (bf16)acc[mi][ni][rj];
                }
            }
        }
    }
}

// ---------------- flash attention: Q,K [B*H,T,64] (Q pre-scaled+roped), Vt [B*H,64,T] ----------------
// Strip-paired for causal balance: wave p does strip 63-p (heavy) then strip p (light),
// 32 rows each -> every wave does exactly 33 kv-block units. 512 blocks x 4 waves.
__global__ __launch_bounds__(256) void k_attn(
    const bf16* __restrict__ Q, const bf16* __restrict__ K,
    const bf16* __restrict__ Vt, bf16* __restrict__ O) {
    __shared__ bf16 lP[128 * 72];   // per-wave-private 32-row stripe (reused across strips)
    int tid = threadIdx.x;
    int l = tid & 63, wid = tid >> 6;
    int p = blockIdx.x * 4 + wid;   // pair index 0..31
    int bh = blockIdx.y;
    const bf16* Kb = K + (size_t)bh * TT * HD;
    const bf16* Vb = Vt + (size_t)bh * HD * TT;
    int b = bh >> 4, h = bh & 15;

    for (int half = 0; half < 2; half++) {
        int s = (half == 0) ? (63 - p) : p;          // heavy strip first
        int r0 = s * 32;
        int nblk = ((r0 + 31) >> 6) + 1;
        const bf16* Qb = Q + ((size_t)bh * TT + r0) * HD;

        bf16x8 qa[2][2];
#pragma unroll
        for (int mi = 0; mi < 2; mi++)
#pragma unroll
            for (int kk = 0; kk < 2; kk++)
                qa[mi][kk] = *(const bf16x8*)(Qb + (size_t)(mi * 16 + (l & 15)) * HD + kk * 32 + (l >> 4) * 8);

        f32x4 oacc[2][4] = {};
        float mrun[2][4], lrun[2][4];
#pragma unroll
        for (int mi = 0; mi < 2; mi++)
#pragma unroll
            for (int rj = 0; rj < 4; rj++) { mrun[mi][rj] = -1e30f; lrun[mi][rj] = 0.0f; }

        for (int j = 0; j < nblk; j++) {
            const bf16* Kj = Kb + (size_t)j * 64 * HD;
            // K fragments
            bf16x8 kb[2][4];
#pragma unroll
            for (int kk = 0; kk < 2; kk++)
#pragma unroll
                for (int nj = 0; nj < 4; nj++)
                    kb[kk][nj] = *(const bf16x8*)(Kj + (size_t)(nj * 16 + (l & 15)) * HD + kk * 32 + (l >> 4) * 8);
            // QK^T
            f32x4 sc[2][4] = {};
#pragma unroll
            for (int kk = 0; kk < 2; kk++)
#pragma unroll
                for (int mi = 0; mi < 2; mi++)
#pragma unroll
                    for (int nj = 0; nj < 4; nj++)
                        sc[mi][nj] = MFMA16(qa[mi][kk], kb[kk][nj], sc[mi][nj]);
            // V fragments hoisted here: latency hidden under softmax
            bf16x8 vb[2][4];
#pragma unroll
            for (int kk = 0; kk < 2; kk++)
#pragma unroll
                for (int nd = 0; nd < 4; nd++)
                    vb[kk][nd] = *(const bf16x8*)(Vb + (size_t)(nd * 16 + (l & 15)) * TT + j * 64 + kk * 32 + (l >> 4) * 8);
            // causal mask (diagonal block is always the last one for a 32-row strip)
            if (j == nblk - 1) {
#pragma unroll
                for (int mi = 0; mi < 2; mi++) {
                    int row0 = r0 + mi * 16 + ((l >> 4) << 2);
#pragma unroll
                    for (int nj = 0; nj < 4; nj++) {
                        int col = j * 64 + nj * 16 + (l & 15);
#pragma unroll
                        for (int rj = 0; rj < 4; rj++)
                            if (col > row0 + rj) sc[mi][nj][rj] = -1e30f;
                    }
                }
            }
            // online softmax
#pragma unroll
            for (int mi = 0; mi < 2; mi++) {
                float rmax[4];
#pragma unroll
                for (int rj = 0; rj < 4; rj++) {
                    float v0 = fmaxf(fmaxf(sc[mi][0][rj], sc[mi][1][rj]),
                                     fmaxf(sc[mi][2][rj], sc[mi][3][rj]));
#pragma unroll
                    for (int off = 1; off < 16; off <<= 1) v0 = fmaxf(v0, __shfl_xor(v0, off, 64));
                    rmax[rj] = v0;
                }
#pragma unroll
                for (int rj = 0; rj < 4; rj++) {
                    float nm = fmaxf(mrun[mi][rj], rmax[rj]);
                    float alpha = __expf(mrun[mi][rj] - nm);
                    mrun[mi][rj] = nm;
                    float ssum = 0.0f;
#pragma unroll
                    for (int nj = 0; nj < 4; nj++) {
                        float pv = __expf(sc[mi][nj][rj] - nm);
                        sc[mi][nj][rj] = pv;
                        ssum += pv;
                    }
#pragma unroll
                    for (int off = 1; off < 16; off <<= 1) ssum += __shfl_xor(ssum, off, 64);
                    lrun[mi][rj] = lrun[mi][rj] * alpha + ssum;
#pragma unroll
                    for (int nd = 0; nd < 4; nd++) oacc[mi][nd][rj] *= alpha;
                }
            }
            // P -> LDS (bf16), per-wave-private rows
#pragma unroll
            for (int mi = 0; mi < 2; mi++) {
                int pr0 = wid * 32 + mi * 16 + ((l >> 4) << 2);
#pragma unroll
                for (int nj = 0; nj < 4; nj++) {
                    int pc = nj * 16 + (l & 15);
#pragma unroll
                    for (int rj = 0; rj < 4; rj++)
                        lP[(pr0 + rj) * 72 + pc] = (bf16)sc[mi][nj][rj];
                }
            }
            // PV
#pragma unroll
            for (int kk = 0; kk < 2; kk++) {
                bf16x8 pa[2];
#pragma unroll
                for (int mi = 0; mi < 2; mi++)
                    pa[mi] = *(const bf16x8*)&lP[(wid * 32 + mi * 16 + (l & 15)) * 72 + kk * 32 + (l >> 4) * 8];
#pragma unroll
                for (int mi = 0; mi < 2; mi++)
#pragma unroll
                    for (int nd = 0; nd < 4; nd++)
                        oacc[mi][nd] = MFMA16(pa[mi], vb[kk][nd], oacc[mi][nd]);
            }
        }
        // epilogue: O[tok][h*64+d] bf16
#pragma unroll
        for (int mi = 0; mi < 2; mi++) {
#pragma unroll
            for (int rj = 0; rj < 4; rj++) {
                int t = r0 + mi * 16 + ((l >> 4) << 2) + rj;
                float inv = 1.0f / lrun[mi][rj];
                size_t base = ((size_t)b * TT + t) * DM + h * HD;
#pragma unroll
                for (int nd = 0; nd < 4; nd++)
                    O[base + nd * 16 + (l & 15)] = (bf16)(oacc[mi][nd][rj] * inv);
            }
        }
    }
}

extern "C" void kernel_launch(void* const* d_in, const int* in_sizes, int n_in,
                              void* d_out, int out_size, void* d_ws, size_t ws_size,
                              hipStream_t stream) {
    const float* x    = (const float*)d_in[0];
    const float* Wqkv = (const float*)d_in[1];
    const float* Wout = (const float*)d_in[2];
    float* out = (float*)d_out;

    char* ws = (char*)d_ws;
    size_t off = 0;
    auto alloc = [&](size_t bytes) {
        void* p = ws + off;
        off += (bytes + 255) & ~(size_t)255;
        return p;
    };
    bf16* xb    = (bf16*)alloc((size_t)TOK * DM * 2);
    bf16* wqkvt = (bf16*)alloc((size_t)NQKV * DM * 2);
    bf16* woutt = (bf16*)alloc((size_t)DM * DM * 2);
    bf16* qr    = (bf16*)alloc((size_t)TOK * DM * 2);
    bf16* kr    = (bf16*)alloc((size_t)TOK * DM * 2);
    bf16* vt    = (bf16*)alloc((size_t)TOK * DM * 2);
    bf16* ob    = (bf16*)alloc((size_t)TOK * DM * 2);
    float* ct   = (float*)alloc((size_t)TT * 32 * 4);
    float* st   = (float*)alloc((size_t)TT * 32 * 4);
    (void)ws_size; (void)in_sizes; (void)n_in; (void)out_size;

    k_cvt<<<TOK * DM / 4 / 256, 256, 0, stream>>>(x, xb, TOK * DM);
    k_transpose_cvt<<<dim3(NQKV / 64, DM / 64), 256, 0, stream>>>(Wqkv, wqkvt, DM, NQKV);
    k_transpose_cvt<<<dim3(DM / 64, DM / 64), 256, 0, stream>>>(Wout, woutt, DM, DM);
    k_rope_tab<<<TT * 32 / 256, 256, 0, stream>>>(ct, st);
    k_gemm_bt<1><<<dim3(NQKV / 128, TOK / 128), 256, 0, stream>>>(
        xb, wqkvt, TOK, NQKV, DM, nullptr, qr, kr, vt);
    k_rope_ip<<<BB * NH * TT / 256, 256, 0, stream>>>(qr, ct, st, 0.125f);
    k_rope_ip<<<BB * NH * TT / 256, 256, 0, stream>>>(kr, ct, st, 1.0f);
    k_attn<<<dim3(8, BB * NH), 256, 0, stream>>>(qr, kr, vt, ob);
    k_gemm_bt<2><<<dim3(DM / 128, TOK / 128), 256, 0, stream>>>(
        ob, woutt, TOK, DM, DM, out, nullptr, nullptr, nullptr);
}